// Round 6
// baseline (2779.601 us; speedup 1.0000x reference)
//
#include <hip/hip_runtime.h>
#include <stdint.h>

// Problem constants
#define HID 100
#define B_TOTAL 512
#define T_IN 1000
#define NB 2
#define BLOCK 1024   // 16 waves -> 4 waves/EU -> 128-VGPR cap (design fits ~115)

// amdgcn builtins use __fp16 vectors on this toolchain (R2 evidence)
typedef __fp16 f16x8 __attribute__((ext_vector_type(8)));
typedef float f32x4 __attribute__((ext_vector_type(4)));

#define MF(A, B, C) __builtin_amdgcn_mfma_f32_16x16x32_f16((A), (B), (C), 0, 0, 0)

__device__ __forceinline__ float sigm(float x) { return 1.0f / (1.0f + __expf(-x)); }
__device__ __forceinline__ float tanh_fast(float x) {
  float e = __expf(2.0f * x);
  return 1.0f - 2.0f / (e + 1.0f);
}

// A-fragment LDS index for element (k, m): tile k>>5, lane ((k&31)>>3)*16+m, elem k&7
// (layout verified correct in R5: absmax 4.88e-4)
__device__ __forceinline__ int aidx(int k, int m) {
  return (k >> 5) * 512 + (((k & 31) >> 3) * 16 + m) * 8 + (k & 7);
}

// weight element fetchers (return f16; 0 in pad regions)
__device__ __forceinline__ __fp16 w1e(const float* Whh1, const float* Wih1, int j, int k) {
  float v = 0.0f;
  if (k < 100) v = Whh1[j * 100 + k];
  else if (k == 100) v = Wih1[j];
  return (__fp16)v;
}
__device__ __forceinline__ __fp16 w2e(const float* Wih2, const float* Whh2, int j, int k) {
  float v = 0.0f;
  if (k < 100) v = Wih2[j * 100 + k];
  else if (k >= 112 && k < 212) v = Whh2[j * 100 + (k - 112)];
  return (__fp16)v;
}

// B-fragment literal builders: element e of frag = B[k = KT*32 + kg*8 + e][n = J's row]
#define MKB1(J, KT) (f16x8){ \
  w1e(Whh1, Wih1, (J), (KT)*32 + kg*8 + 0), w1e(Whh1, Wih1, (J), (KT)*32 + kg*8 + 1), \
  w1e(Whh1, Wih1, (J), (KT)*32 + kg*8 + 2), w1e(Whh1, Wih1, (J), (KT)*32 + kg*8 + 3), \
  w1e(Whh1, Wih1, (J), (KT)*32 + kg*8 + 4), w1e(Whh1, Wih1, (J), (KT)*32 + kg*8 + 5), \
  w1e(Whh1, Wih1, (J), (KT)*32 + kg*8 + 6), w1e(Whh1, Wih1, (J), (KT)*32 + kg*8 + 7) }
#define MKB2(J, KT) (f16x8){ \
  w2e(Wih2, Whh2, (J), (KT)*32 + kg*8 + 0), w2e(Wih2, Whh2, (J), (KT)*32 + kg*8 + 1), \
  w2e(Wih2, Whh2, (J), (KT)*32 + kg*8 + 2), w2e(Wih2, Whh2, (J), (KT)*32 + kg*8 + 3), \
  w2e(Wih2, Whh2, (J), (KT)*32 + kg*8 + 4), w2e(Wih2, Whh2, (J), (KT)*32 + kg*8 + 5), \
  w2e(Wih2, Whh2, (J), (KT)*32 + kg*8 + 6), w2e(Wih2, Whh2, (J), (KT)*32 + kg*8 + 7) }

__global__ __launch_bounds__(BLOCK, 4) void lstm2_mfma(
    const float* __restrict__ input,  // [512,1000]
    const float* __restrict__ Wih1,   // [400,1]
    const float* __restrict__ Whh1,   // [400,100]
    const float* __restrict__ bih1,
    const float* __restrict__ bhh1,
    const float* __restrict__ Wih2,   // [400,100]
    const float* __restrict__ Whh2,   // [400,100]
    const float* __restrict__ bih2,
    const float* __restrict__ bhh2,
    const float* __restrict__ Wlin,   // [1,100]
    const float* __restrict__ blin,   // [1]
    const int* __restrict__ futp,
    float* __restrict__ out)          // [512, 1000+future]
{
  __shared__ __align__(16) __fp16 A1h[4 * 512];   // L1 A: k0..99=h1(t-1), k100=x(t)
  __shared__ __align__(16) __fp16 A2h[7 * 512];   // L2 A: k0..99=h1(t), k112..211=h2(t-1)
  __shared__ __align__(16) __fp16 BL1h[4 * 512];  // B frags, N-tile 24 (pair 0 reads)
  __shared__ __align__(16) __fp16 BL2h[7 * 512];
  __shared__ float gpart[2][400][2];  // K-half partial gates [kh][n][batch]
  __shared__ float xrow[NB][T_IN];    // staged inputs (8 KB)
  __shared__ float ybuf[NB][104];     // h2(t) f32 for y-dot (pads 0)
  __shared__ float wls[104];          // Wlin staged (pads 0)

  const int tid = threadIdx.x;
  const int lane = tid & 63;
  const int wv = tid >> 6;    // 0..15
  const int pr = wv >> 1;     // N-tile group 0..7
  const int kh = wv & 1;      // K-half
  const int b0 = blockIdx.x * NB;
  const int F = futp[0];
  const int TT = T_IN + F;

  // ---------------- init: stage + zero ----------------
  for (int i = tid; i < NB * T_IN; i += BLOCK) {
    int b = i / T_IN, t = i % T_IN;
    xrow[b][t] = input[(size_t)(b0 + b) * T_IN + t];
  }
  for (int i = tid; i < 1024; i += BLOCK) ((uint32_t*)A1h)[i] = 0u;
  for (int i = tid; i < 1792; i += BLOCK) ((uint32_t*)A2h)[i] = 0u;
  if (tid < 104) wls[tid] = (tid < HID) ? Wlin[tid] : 0.0f;
  if (tid < 208) ((float*)ybuf)[tid] = 0.0f;

  // ---------------- register-resident B fragments ----------------
  const int n15 = lane & 15;
  const int kg = (lane >> 4) & 3;
  const int j0 = pr * 16 + n15;         // N-tile pr
  const int j1 = (8 + pr) * 16 + n15;   // N-tile 8+pr
  const int j2 = (16 + pr) * 16 + n15;  // N-tile 16+pr
  // L1: K-half kh covers KT {2kh, 2kh+1} (k = 64*kh .. 64*kh+63)
  f16x8 B1_0_0 = MKB1(j0, kh * 2 + 0), B1_0_1 = MKB1(j0, kh * 2 + 1);
  f16x8 B1_1_0 = MKB1(j1, kh * 2 + 0), B1_1_1 = MKB1(j1, kh * 2 + 1);
  f16x8 B1_2_0 = MKB1(j2, kh * 2 + 0), B1_2_1 = MKB1(j2, kh * 2 + 1);
  // L2: even waves KT {0,1,2} (k 0..95); odd waves KT {3,4,5} + KT 6 (k 96..223)
  f16x8 B2_0_0 = MKB2(j0, kh * 3 + 0), B2_0_1 = MKB2(j0, kh * 3 + 1), B2_0_2 = MKB2(j0, kh * 3 + 2);
  f16x8 B2_1_0 = MKB2(j1, kh * 3 + 0), B2_1_1 = MKB2(j1, kh * 3 + 1), B2_1_2 = MKB2(j1, kh * 3 + 2);
  f16x8 B2_2_0 = MKB2(j2, kh * 3 + 0), B2_2_1 = MKB2(j2, kh * 3 + 1), B2_2_2 = MKB2(j2, kh * 3 + 2);
  f16x8 B2x_0 = MKB2(j0, 6), B2x_1 = MKB2(j1, 6), B2x_2 = MKB2(j2, 6);  // odd-wave 4th frag

  // N-tile 24 fragments -> LDS (tids 0..63 emulate one wave's lanes; verified in R5)
  if (tid < 64) {
    int jj = 384 + n15;
    f16x8* BV1 = (f16x8*)BL1h;
    f16x8* BV2 = (f16x8*)BL2h;
    BV1[0 * 64 + tid] = MKB1(jj, 0); BV1[1 * 64 + tid] = MKB1(jj, 1);
    BV1[2 * 64 + tid] = MKB1(jj, 2); BV1[3 * 64 + tid] = MKB1(jj, 3);
    BV2[0 * 64 + tid] = MKB2(jj, 0); BV2[1 * 64 + tid] = MKB2(jj, 1);
    BV2[2 * 64 + tid] = MKB2(jj, 2); BV2[3 * 64 + tid] = MKB2(jj, 3);
    BV2[4 * 64 + tid] = MKB2(jj, 4); BV2[5 * 64 + tid] = MKB2(jj, 5);
    BV2[6 * 64 + tid] = MKB2(jj, 6);
  }

  // partial-gate write pointer for this wave's K-slot
  float2* gp2 = ((float2*)gpart) + kh * 400;

  // ---------------- act duty: tids 512..711 (waves 8-11) ----------------
  const int is_act = (tid >= 512 && tid < 512 + NB * HID);
  const int ab = (tid - 512) & 1;
  const int ak = (tid - 512) >> 1;
  float b1i = 0, b1f = 0, b1g = 0, b1o = 0, b2i = 0, b2f = 0, b2g = 0, b2o = 0;
  if (is_act) {
    b1i = bih1[ak] + bhh1[ak];             b1f = bih1[ak + 100] + bhh1[ak + 100];
    b1g = bih1[ak + 200] + bhh1[ak + 200]; b1o = bih1[ak + 300] + bhh1[ak + 300];
    b2i = bih2[ak] + bhh2[ak];             b2f = bih2[ak + 100] + bhh2[ak + 100];
    b2g = bih2[ak + 200] + bhh2[ak + 200]; b2o = bih2[ak + 300] + bhh2[ak + 300];
  }
  float c1v = 0.0f, c2v = 0.0f;

  // ---------------- y duty: tids 1008..1023 (wave 15) ----------------
  const int is_y = (tid >= 1008);
  const int ybat = ((tid - 1008) >> 3) & 1;
  const int yl = (tid - 1008) & 7;
  const float blin0 = blin[0];

  __syncthreads();
  if (tid >= 712 && tid < 714) A1h[aidx(100, tid - 712)] = (__fp16)xrow[tid - 712][0];

#define L1_PHASE { \
    const f16x8* A1v = (const f16x8*)A1h; \
    f16x8 a0 = A1v[(kh * 2 + 0) * 64 + lane], a1 = A1v[(kh * 2 + 1) * 64 + lane]; \
    f32x4 c0 = {0.f,0.f,0.f,0.f}, c1 = {0.f,0.f,0.f,0.f}, c2 = {0.f,0.f,0.f,0.f}; \
    c0 = MF(a0, B1_0_0, c0); c0 = MF(a1, B1_0_1, c0); \
    c1 = MF(a0, B1_1_0, c1); c1 = MF(a1, B1_1_1, c1); \
    c2 = MF(a0, B1_2_0, c2); c2 = MF(a1, B1_2_1, c2); \
    if (pr == 0) { \
      const f16x8* Bv = (const f16x8*)BL1h; \
      f32x4 c3 = {0.f,0.f,0.f,0.f}; \
      c3 = MF(a0, Bv[(kh * 2 + 0) * 64 + lane], c3); \
      c3 = MF(a1, Bv[(kh * 2 + 1) * 64 + lane], c3); \
      if (lane < 16) gp2[384 + lane] = float2{c3[0], c3[1]}; \
    } \
    if (lane < 16) { \
      gp2[(pr << 4) + lane] = float2{c0[0], c0[1]}; \
      gp2[((8 + pr) << 4) + lane] = float2{c1[0], c1[1]}; \
      gp2[((16 + pr) << 4) + lane] = float2{c2[0], c2[1]}; \
    } }

#define L2_PHASE { \
    const f16x8* A2v = (const f16x8*)A2h; \
    f16x8 a0 = A2v[(kh * 3 + 0) * 64 + lane], a1 = A2v[(kh * 3 + 1) * 64 + lane], \
          a2 = A2v[(kh * 3 + 2) * 64 + lane]; \
    f32x4 c0 = {0.f,0.f,0.f,0.f}, c1 = {0.f,0.f,0.f,0.f}, c2 = {0.f,0.f,0.f,0.f}; \
    c0 = MF(a0, B2_0_0, c0); c0 = MF(a1, B2_0_1, c0); c0 = MF(a2, B2_0_2, c0); \
    c1 = MF(a0, B2_1_0, c1); c1 = MF(a1, B2_1_1, c1); c1 = MF(a2, B2_1_2, c1); \
    c2 = MF(a0, B2_2_0, c2); c2 = MF(a1, B2_2_1, c2); c2 = MF(a2, B2_2_2, c2); \
    if (kh) { \
      f16x8 ax = A2v[6 * 64 + lane]; \
      c0 = MF(ax, B2x_0, c0); c1 = MF(ax, B2x_1, c1); c2 = MF(ax, B2x_2, c2); \
    } \
    if (pr == 0) { \
      const f16x8* Bv = (const f16x8*)BL2h; \
      f32x4 c3 = {0.f,0.f,0.f,0.f}; \
      c3 = MF(a0, Bv[(kh * 3 + 0) * 64 + lane], c3); \
      c3 = MF(a1, Bv[(kh * 3 + 1) * 64 + lane], c3); \
      c3 = MF(a2, Bv[(kh * 3 + 2) * 64 + lane], c3); \
      if (kh) { f16x8 ax2 = A2v[6 * 64 + lane]; c3 = MF(ax2, Bv[6 * 64 + lane], c3); } \
      if (lane < 16) gp2[384 + lane] = float2{c3[0], c3[1]}; \
    } \
    if (lane < 16) { \
      gp2[(pr << 4) + lane] = float2{c0[0], c0[1]}; \
      gp2[((8 + pr) << 4) + lane] = float2{c1[0], c1[1]}; \
      gp2[((16 + pr) << 4) + lane] = float2{c2[0], c2[1]}; \
    } }

#define ACT1_BODY { \
    const float* gpf = (const float*)gpart; \
    float gi = gpf[(ak) * 2 + ab]        + gpf[800 + (ak) * 2 + ab]        + b1i; \
    float gf = gpf[(ak + 100) * 2 + ab]  + gpf[800 + (ak + 100) * 2 + ab]  + b1f; \
    float gg = gpf[(ak + 200) * 2 + ab]  + gpf[800 + (ak + 200) * 2 + ab]  + b1g; \
    float go = gpf[(ak + 300) * 2 + ab]  + gpf[800 + (ak + 300) * 2 + ab]  + b1o; \
    c1v = sigm(gf) * c1v + sigm(gi) * tanh_fast(gg); \
    __fp16 h = (__fp16)(sigm(go) * tanh_fast(c1v)); \
    A1h[aidx(ak, ab)] = h; A2h[aidx(ak, ab)] = h; }

#define ACT2_BODY { \
    const float* gpf = (const float*)gpart; \
    float gi = gpf[(ak) * 2 + ab]        + gpf[800 + (ak) * 2 + ab]        + b2i; \
    float gf = gpf[(ak + 100) * 2 + ab]  + gpf[800 + (ak + 100) * 2 + ab]  + b2f; \
    float gg = gpf[(ak + 200) * 2 + ab]  + gpf[800 + (ak + 200) * 2 + ab]  + b2g; \
    float go = gpf[(ak + 300) * 2 + ab]  + gpf[800 + (ak + 300) * 2 + ab]  + b2o; \
    c2v = sigm(gf) * c2v + sigm(gi) * tanh_fast(gg); \
    float hv = sigm(go) * tanh_fast(c2v); \
    A2h[aidx(112 + ak, ab)] = (__fp16)hv; ybuf[ab][ak] = hv; }

#define Y_BODY(tt, FEED) { \
    float s = 0.0f; \
    _Pragma("unroll") \
    for (int m = 0; m < 13; m++) s = fmaf(ybuf[ybat][yl + 8 * m], wls[yl + 8 * m], s); \
    s += __shfl_down(s, 4, 8); \
    s += __shfl_down(s, 2, 8); \
    s += __shfl_down(s, 1, 8); \
    if (yl == 0) { \
      float y = s + blin0; \
      out[(size_t)(b0 + ybat) * TT + (tt)] = y; \
      if (FEED) A1h[aidx(100, ybat)] = (__fp16)y; \
    } }

  // ================= teacher-forced phase: 4 barriers/step =================
  for (int t = 0; t < T_IN; t++) {
    __syncthreads();  // A: A1(h1(t-1), x(t)), A2(h2(t-1)) ready; ybuf(t-1) ready
    L1_PHASE
    if (is_y && t > 0) Y_BODY(t - 1, 0)   // y(t-1) off critical path
    __syncthreads();  // B: gpart (L1) ready
    if (is_act) ACT1_BODY
    if (tid >= 712 && tid < 714 && t + 1 < T_IN)
      A1h[aidx(100, tid - 712)] = (__fp16)xrow[tid - 712][t + 1];
    __syncthreads();  // C: A2(h1(t)) ready; gpart free
    L2_PHASE
    __syncthreads();  // D: gpart (L2) ready
    if (is_act) ACT2_BODY
  }

  // ================= autoregressive phase: 5 barriers/step =================
  for (int t = T_IN; t < TT; t++) {
    __syncthreads();  // ybuf(t-1) ready
    if (is_y) Y_BODY(t - 1, 1)            // y(t-1) -> out + x(t) feed into A1
    __syncthreads();  // A1 x ready
    L1_PHASE
    __syncthreads();
    if (is_act) ACT1_BODY
    __syncthreads();
    L2_PHASE
    __syncthreads();
    if (is_act) ACT2_BODY
  }
  __syncthreads();
  if (is_y) Y_BODY(TT - 1, 0)             // final y
}

extern "C" void kernel_launch(void* const* d_in, const int* in_sizes, int n_in,
                              void* d_out, int out_size, void* d_ws, size_t ws_size,
                              hipStream_t stream) {
  const float* input = (const float*)d_in[0];
  const float* Wih1  = (const float*)d_in[1];
  const float* Whh1  = (const float*)d_in[2];
  const float* bih1  = (const float*)d_in[3];
  const float* bhh1  = (const float*)d_in[4];
  const float* Wih2  = (const float*)d_in[5];
  const float* Whh2  = (const float*)d_in[6];
  const float* bih2  = (const float*)d_in[7];
  const float* bhh2  = (const float*)d_in[8];
  const float* Wlin  = (const float*)d_in[9];
  const float* blin  = (const float*)d_in[10];
  const int*   futp  = (const int*)d_in[11];
  float* out = (float*)d_out;

  dim3 grid(B_TOTAL / NB);  // 256 blocks, 1 per CU
  dim3 block(BLOCK);
  hipLaunchKernelGGL(lstm2_mfma, grid, block, 0, stream,
                     input, Wih1, Whh1, bih1, bhh1, Wih2, Whh2, bih2, bhh2,
                     Wlin, blin, futp, out);
}

// Round 8
// 2039.283 us; speedup vs baseline: 1.3630x; 1.3630x over previous
//
#include <hip/hip_runtime.h>
#include <stdint.h>

// Problem constants
#define HID 100
#define B_TOTAL 512
#define T_IN 1000
#define NB 2
#define BLOCK 512   // 8 waves, 2 waves/EU

typedef __fp16 f16x8 __attribute__((ext_vector_type(8)));
typedef float f32x4 __attribute__((ext_vector_type(4)));
typedef int   i32x4 __attribute__((ext_vector_type(4)));

#define MF(A, B, C) __builtin_amdgcn_mfma_f32_16x16x32_f16((A), (B), (C), 0, 0, 0)

__device__ __forceinline__ float sigm(float x) { return 1.0f / (1.0f + __expf(-x)); }
__device__ __forceinline__ float tanh_fast(float x) {
  float e = __expf(2.0f * x);
  return 1.0f - 2.0f / (e + 1.0f);
}

// ---- compact A layout: per 32-K tile, 80 f16 elems (160 B):
//   elems [0..31]  = row m=0, k 0..31 of the tile
//   elems [32..63] = row m=1
//   elems [64..71] = shared 16B zero chunk (read by all m>=2 lanes, broadcast)
//   elems [72..79] = pad (keeps tile stride 160 B, 16B-aligned)
__device__ __forceinline__ int cidx(int k, int m) {   // write-side index
  return (k >> 5) * 80 + m * 32 + (k & 31);
}

// weight element fetchers (0 in pad regions)
__device__ __forceinline__ __fp16 w1e(const float* Whh1, const float* Wih1, int j, int k) {
  float v = 0.0f;
  if (k < 100) v = Whh1[j * 100 + k];
  else if (k == 100) v = Wih1[j];
  return (__fp16)v;
}
__device__ __forceinline__ __fp16 w2e(const float* Wih2, const float* Whh2, int j, int k) {
  float v = 0.0f;
  if (k < 100) v = Wih2[j * 100 + k];
  else if (k >= 112 && k < 212) v = Whh2[j * 100 + (k - 112)];
  return (__fp16)v;
}

#define MKB1(J, KT) (f16x8){ \
  w1e(Whh1, Wih1, (J), (KT)*32 + kg*8 + 0), w1e(Whh1, Wih1, (J), (KT)*32 + kg*8 + 1), \
  w1e(Whh1, Wih1, (J), (KT)*32 + kg*8 + 2), w1e(Whh1, Wih1, (J), (KT)*32 + kg*8 + 3), \
  w1e(Whh1, Wih1, (J), (KT)*32 + kg*8 + 4), w1e(Whh1, Wih1, (J), (KT)*32 + kg*8 + 5), \
  w1e(Whh1, Wih1, (J), (KT)*32 + kg*8 + 6), w1e(Whh1, Wih1, (J), (KT)*32 + kg*8 + 7) }
#define MKB2(J, KT) (f16x8){ \
  w2e(Wih2, Whh2, (J), (KT)*32 + kg*8 + 0), w2e(Wih2, Whh2, (J), (KT)*32 + kg*8 + 1), \
  w2e(Wih2, Whh2, (J), (KT)*32 + kg*8 + 2), w2e(Wih2, Whh2, (J), (KT)*32 + kg*8 + 3), \
  w2e(Wih2, Whh2, (J), (KT)*32 + kg*8 + 4), w2e(Wih2, Whh2, (J), (KT)*32 + kg*8 + 5), \
  w2e(Wih2, Whh2, (J), (KT)*32 + kg*8 + 6), w2e(Wih2, Whh2, (J), (KT)*32 + kg*8 + 7) }

__global__ __launch_bounds__(BLOCK, 2) void lstm2_mfma(
    const float* __restrict__ input,  // [512,1000]
    const float* __restrict__ Wih1,   // [400,1]
    const float* __restrict__ Whh1,   // [400,100]
    const float* __restrict__ bih1,
    const float* __restrict__ bhh1,
    const float* __restrict__ Wih2,   // [400,100]
    const float* __restrict__ Whh2,   // [400,100]
    const float* __restrict__ bih2,
    const float* __restrict__ bhh2,
    const float* __restrict__ Wlin,   // [1,100]
    const float* __restrict__ blin,   // [1]
    const int* __restrict__ futp,
    float* __restrict__ out)          // [512, 1000+future]
{
  __shared__ __align__(16) __fp16 A1c[4 * 80];    // L1 A compact: k0..99=h1(t-1), k100=x(t)
  __shared__ __align__(16) __fp16 A2c[7 * 80];    // L2 A compact: k0..99=h1(t), k112..211=h2(t-1)
  __shared__ __align__(16) __fp16 BL1h[4 * 512];  // B frags, N-tile 24 (wave 0 reads, full layout)
  __shared__ __align__(16) __fp16 BL2h[7 * 512];
  __shared__ float2 gb2[400];        // gate pre-acts [n](batch0, batch1)
  __shared__ float xrow[NB][T_IN];   // staged inputs (8 KB)
  __shared__ float ybuf[NB][104];    // h2(t) f32 for y-dot (pads 0)
  __shared__ float wls[104];         // Wlin staged (pads 0)

  const int tid = threadIdx.x;
  const int lane = tid & 63;
  const int wv = tid >> 6;
  const int b0 = blockIdx.x * NB;
  const int F = futp[0];
  const int TT = T_IN + F;

  // ---------------- init: stage + zero ----------------
  for (int i = tid; i < NB * T_IN; i += BLOCK) {
    int b = i / T_IN, t = i % T_IN;
    xrow[b][t] = input[(size_t)(b0 + b) * T_IN + t];
  }
  if (tid < 160) ((uint32_t*)A1c)[tid] = 0u;   // whole compact buffer incl. zero chunks
  if (tid < 280) ((uint32_t*)A2c)[tid] = 0u;
  if (tid < 104) wls[tid] = (tid < HID) ? Wlin[tid] : 0.0f;
  if (tid < 208) ((float*)ybuf)[tid] = 0.0f;

  // ---------------- register-resident B fragments (intrinsic path, verified R5) ----
  const int n15 = lane & 15;
  const int kg = (lane >> 4) & 3;
  const int j0 = (wv) * 16 + n15;        // N-tile wv
  const int j1 = (8 + wv) * 16 + n15;    // N-tile 8+wv
  const int j2 = (16 + wv) * 16 + n15;   // N-tile 16+wv
  f16x8 B1_0_0 = MKB1(j0, 0), B1_0_1 = MKB1(j0, 1), B1_0_2 = MKB1(j0, 2), B1_0_3 = MKB1(j0, 3);
  f16x8 B1_1_0 = MKB1(j1, 0), B1_1_1 = MKB1(j1, 1), B1_1_2 = MKB1(j1, 2), B1_1_3 = MKB1(j1, 3);
  f16x8 B1_2_0 = MKB1(j2, 0), B1_2_1 = MKB1(j2, 1), B1_2_2 = MKB1(j2, 2), B1_2_3 = MKB1(j2, 3);
  f16x8 B2_0_0 = MKB2(j0, 0), B2_0_1 = MKB2(j0, 1), B2_0_2 = MKB2(j0, 2), B2_0_3 = MKB2(j0, 3),
        B2_0_4 = MKB2(j0, 4), B2_0_5 = MKB2(j0, 5), B2_0_6 = MKB2(j0, 6);
  f16x8 B2_1_0 = MKB2(j1, 0), B2_1_1 = MKB2(j1, 1), B2_1_2 = MKB2(j1, 2), B2_1_3 = MKB2(j1, 3),
        B2_1_4 = MKB2(j1, 4), B2_1_5 = MKB2(j1, 5), B2_1_6 = MKB2(j1, 6);
  f16x8 B2_2_0 = MKB2(j2, 0), B2_2_1 = MKB2(j2, 1), B2_2_2 = MKB2(j2, 2), B2_2_3 = MKB2(j2, 3),
        B2_2_4 = MKB2(j2, 4), B2_2_5 = MKB2(j2, 5), B2_2_6 = MKB2(j2, 6);

  // N-tile 24 fragments -> LDS (tids 0..63 emulate one wave's lanes; verified R5)
  if (tid < 64) {
    int jj = 384 + n15;
    f16x8* BV1 = (f16x8*)BL1h;
    f16x8* BV2 = (f16x8*)BL2h;
    BV1[0 * 64 + tid] = MKB1(jj, 0); BV1[1 * 64 + tid] = MKB1(jj, 1);
    BV1[2 * 64 + tid] = MKB1(jj, 2); BV1[3 * 64 + tid] = MKB1(jj, 3);
    BV2[0 * 64 + tid] = MKB2(jj, 0); BV2[1 * 64 + tid] = MKB2(jj, 1);
    BV2[2 * 64 + tid] = MKB2(jj, 2); BV2[3 * 64 + tid] = MKB2(jj, 3);
    BV2[4 * 64 + tid] = MKB2(jj, 4); BV2[5 * 64 + tid] = MKB2(jj, 5);
    BV2[6 * 64 + tid] = MKB2(jj, 6);
  }

  // compact-A read offset (f16 elems, loop-invariant): real lanes (m<2) read their
  // 16B chunk; all m>=2 lanes read the tile's shared zero chunk (LDS broadcast).
  const int roff = (n15 < 2) ? (n15 * 32 + kg * 8) : 64;

  // ---------------- act duty: tids 256..455 -> (b, k) ----------------
  const int is_act = (tid >= 256 && tid < 256 + NB * HID);
  const int ab = (tid - 256) & 1;
  const int ak = (tid - 256) >> 1;
  float b1i = 0, b1f = 0, b1g = 0, b1o = 0, b2i = 0, b2f = 0, b2g = 0, b2o = 0;
  if (is_act) {
    b1i = bih1[ak] + bhh1[ak];             b1f = bih1[ak + 100] + bhh1[ak + 100];
    b1g = bih1[ak + 200] + bhh1[ak + 200]; b1o = bih1[ak + 300] + bhh1[ak + 300];
    b2i = bih2[ak] + bhh2[ak];             b2f = bih2[ak + 100] + bhh2[ak + 100];
    b2g = bih2[ak + 200] + bhh2[ak + 200]; b2o = bih2[ak + 300] + bhh2[ak + 300];
  }
  float c1v = 0.0f, c2v = 0.0f;

  // ---------------- y duty: tids 496..511 ----------------
  const int is_y = (tid >= 496);
  const int ybat = ((tid - 496) >> 3) & 1;
  const int yl = (tid - 496) & 7;
  const float blin0 = blin[0];

  __syncthreads();
  if (tid >= 464 && tid < 466) A1c[cidx(100, tid - 464)] = (__fp16)xrow[tid - 464][0];

#define RDA(BUF, t) (*(const f16x8*)&(BUF)[(t) * 80 + roff])

#define L1_PHASE { \
    f16x8 a0 = RDA(A1c, 0), a1 = RDA(A1c, 1), a2 = RDA(A1c, 2), a3 = RDA(A1c, 3); \
    f32x4 c0 = {0.f,0.f,0.f,0.f}, c1 = {0.f,0.f,0.f,0.f}, c2 = {0.f,0.f,0.f,0.f}; \
    c0 = MF(a0, B1_0_0, c0); c0 = MF(a1, B1_0_1, c0); c0 = MF(a2, B1_0_2, c0); c0 = MF(a3, B1_0_3, c0); \
    c1 = MF(a0, B1_1_0, c1); c1 = MF(a1, B1_1_1, c1); c1 = MF(a2, B1_1_2, c1); c1 = MF(a3, B1_1_3, c1); \
    c2 = MF(a0, B1_2_0, c2); c2 = MF(a1, B1_2_1, c2); c2 = MF(a2, B1_2_2, c2); c2 = MF(a3, B1_2_3, c2); \
    if (wv == 0) { \
      const f16x8* Bv = (const f16x8*)BL1h; \
      f32x4 c3 = {0.f,0.f,0.f,0.f}; \
      c3 = MF(a0, Bv[lane], c3); c3 = MF(a1, Bv[64 + lane], c3); \
      c3 = MF(a2, Bv[128 + lane], c3); c3 = MF(a3, Bv[192 + lane], c3); \
      if (lane < 16) gb2[384 + lane] = float2{c3[0], c3[1]}; \
    } \
    if (lane < 16) { \
      gb2[(wv << 4) + lane] = float2{c0[0], c0[1]}; \
      gb2[((8 + wv) << 4) + lane] = float2{c1[0], c1[1]}; \
      gb2[((16 + wv) << 4) + lane] = float2{c2[0], c2[1]}; \
    } }

#define L2_PHASE { \
    f16x8 a0 = RDA(A2c, 0), a1 = RDA(A2c, 1), a2 = RDA(A2c, 2), a3 = RDA(A2c, 3), \
          a4 = RDA(A2c, 4), a5 = RDA(A2c, 5), a6 = RDA(A2c, 6); \
    f32x4 c0 = {0.f,0.f,0.f,0.f}, c1 = {0.f,0.f,0.f,0.f}, c2 = {0.f,0.f,0.f,0.f}; \
    c0 = MF(a0, B2_0_0, c0); c0 = MF(a1, B2_0_1, c0); c0 = MF(a2, B2_0_2, c0); c0 = MF(a3, B2_0_3, c0); \
    c0 = MF(a4, B2_0_4, c0); c0 = MF(a5, B2_0_5, c0); c0 = MF(a6, B2_0_6, c0); \
    c1 = MF(a0, B2_1_0, c1); c1 = MF(a1, B2_1_1, c1); c1 = MF(a2, B2_1_2, c1); c1 = MF(a3, B2_1_3, c1); \
    c1 = MF(a4, B2_1_4, c1); c1 = MF(a5, B2_1_5, c1); c1 = MF(a6, B2_1_6, c1); \
    c2 = MF(a0, B2_2_0, c2); c2 = MF(a1, B2_2_1, c2); c2 = MF(a2, B2_2_2, c2); c2 = MF(a3, B2_2_3, c2); \
    c2 = MF(a4, B2_2_4, c2); c2 = MF(a5, B2_2_5, c2); c2 = MF(a6, B2_2_6, c2); \
    if (wv == 0) { \
      const f16x8* Bv = (const f16x8*)BL2h; \
      f32x4 c3 = {0.f,0.f,0.f,0.f}; \
      c3 = MF(a0, Bv[lane], c3); c3 = MF(a1, Bv[64 + lane], c3); c3 = MF(a2, Bv[128 + lane], c3); \
      c3 = MF(a3, Bv[192 + lane], c3); c3 = MF(a4, Bv[256 + lane], c3); c3 = MF(a5, Bv[320 + lane], c3); \
      c3 = MF(a6, Bv[384 + lane], c3); \
      if (lane < 16) gb2[384 + lane] = float2{c3[0], c3[1]}; \
    } \
    if (lane < 16) { \
      gb2[(wv << 4) + lane] = float2{c0[0], c0[1]}; \
      gb2[((8 + wv) << 4) + lane] = float2{c1[0], c1[1]}; \
      gb2[((16 + wv) << 4) + lane] = float2{c2[0], c2[1]}; \
    } }

#define ACT1_BODY { \
    const float* gbf = (const float*)gb2; \
    float gi = gbf[(ak) * 2 + ab] + b1i; \
    float gf = gbf[(ak + 100) * 2 + ab] + b1f; \
    float gg = gbf[(ak + 200) * 2 + ab] + b1g; \
    float go = gbf[(ak + 300) * 2 + ab] + b1o; \
    c1v = sigm(gf) * c1v + sigm(gi) * tanh_fast(gg); \
    __fp16 h = (__fp16)(sigm(go) * tanh_fast(c1v)); \
    A1c[cidx(ak, ab)] = h; A2c[cidx(ak, ab)] = h; }

#define ACT2_BODY { \
    const float* gbf = (const float*)gb2; \
    float gi = gbf[(ak) * 2 + ab] + b2i; \
    float gf = gbf[(ak + 100) * 2 + ab] + b2f; \
    float gg = gbf[(ak + 200) * 2 + ab] + b2g; \
    float go = gbf[(ak + 300) * 2 + ab] + b2o; \
    c2v = sigm(gf) * c2v + sigm(gi) * tanh_fast(gg); \
    float hv = sigm(go) * tanh_fast(c2v); \
    A2c[cidx(112 + ak, ab)] = (__fp16)hv; ybuf[ab][ak] = hv; }

#define Y_BODY(tt, FEED) { \
    float s = 0.0f; \
    _Pragma("unroll") \
    for (int m = 0; m < 13; m++) s = fmaf(ybuf[ybat][yl + 8 * m], wls[yl + 8 * m], s); \
    s += __shfl_down(s, 4, 8); \
    s += __shfl_down(s, 2, 8); \
    s += __shfl_down(s, 1, 8); \
    if (yl == 0) { \
      float y = s + blin0; \
      out[(size_t)(b0 + ybat) * TT + (tt)] = y; \
      if (FEED) A1c[cidx(100, ybat)] = (__fp16)y; \
    } }

  // ================= teacher-forced phase: 4 barriers/step =================
  for (int t = 0; t < T_IN; t++) {
    __syncthreads();  // A1(h1(t-1), x(t)), A2(h2(t-1)) ready; ybuf(t-1) ready
    L1_PHASE
    if (is_y && t > 0) Y_BODY(t - 1, 0)   // y(t-1) off critical path
    __syncthreads();  // gb2 (L1) ready
    if (is_act) ACT1_BODY
    if (tid >= 464 && tid < 466 && t + 1 < T_IN)
      A1c[cidx(100, tid - 464)] = (__fp16)xrow[tid - 464][t + 1];
    __syncthreads();  // A2(h1(t)) ready; gb2 free
    L2_PHASE
    __syncthreads();  // gb2 (L2) ready
    if (is_act) ACT2_BODY
  }

  // ================= autoregressive phase: 5 barriers/step =================
  for (int t = T_IN; t < TT; t++) {
    __syncthreads();  // ybuf(t-1) ready
    if (is_y) Y_BODY(t - 1, 1)            // y(t-1) -> out + x(t) feed into A1
    __syncthreads();  // A1 x ready
    L1_PHASE
    __syncthreads();
    if (is_act) ACT1_BODY
    __syncthreads();
    L2_PHASE
    __syncthreads();
    if (is_act) ACT2_BODY
  }
  __syncthreads();
  if (is_y) Y_BODY(TT - 1, 0)             // final y
}

extern "C" void kernel_launch(void* const* d_in, const int* in_sizes, int n_in,
                              void* d_out, int out_size, void* d_ws, size_t ws_size,
                              hipStream_t stream) {
  const float* input = (const float*)d_in[0];
  const float* Wih1  = (const float*)d_in[1];
  const float* Whh1  = (const float*)d_in[2];
  const float* bih1  = (const float*)d_in[3];
  const float* bhh1  = (const float*)d_in[4];
  const float* Wih2  = (const float*)d_in[5];
  const float* Whh2  = (const float*)d_in[6];
  const float* bih2  = (const float*)d_in[7];
  const float* bhh2  = (const float*)d_in[8];
  const float* Wlin  = (const float*)d_in[9];
  const float* blin  = (const float*)d_in[10];
  const int*   futp  = (const int*)d_in[11];
  float* out = (float*)d_out;

  dim3 grid(B_TOTAL / NB);  // 256 blocks, 1 per CU
  dim3 block(BLOCK);
  hipLaunchKernelGGL(lstm2_mfma, grid, block, 0, stream,
                     input, Wih1, Whh1, bih1, bhh1, Wih2, Whh2, bih2, bhh2,
                     Wlin, blin, futp, out);
}